// Round 4
// baseline (181.493 us; speedup 1.0000x reference)
//
#include <hip/hip_runtime.h>
#include <math.h>

#define H2 256
#define MAXDEG 128

typedef __attribute__((ext_vector_type(8))) short bf16x8;
typedef __attribute__((ext_vector_type(4))) float f32x4;

// round-to-nearest-even fp32 -> bf16 (as ushort)
__device__ __forceinline__ unsigned short bf16_rnd(float x) {
    union { float f; unsigned u; } c; c.f = x;
    return (unsigned short)((c.u + 0x7FFFu + ((c.u >> 16) & 1u)) >> 16);
}
__device__ __forceinline__ float bf16_tof(unsigned short h) {
    union { float f; unsigned u; } c; c.u = ((unsigned)h) << 16;
    return c.f;
}
__device__ __forceinline__ void split2(float x, unsigned short& hi, unsigned short& lo) {
    hi = bf16_rnd(x);
    lo = bf16_rnd(x - bf16_tof(hi));
}
__device__ __forceinline__ float u2f_lo(unsigned u) {
    union { float f; unsigned u; } c; c.u = u << 16; return c.f;
}
__device__ __forceinline__ float u2f_hi(unsigned u) {
    union { float f; unsigned u; } c; c.u = u & 0xFFFF0000u; return c.f;
}

// ---------------------------------------------------------------------------
// Fused prep: zero cursor; nf fp32 -> cat hi/lo bf16 cols [0,256);
// W1[512][256]->W1t[256][512] hi/lo; W2[256][256]->W2t[256][256] hi/lo.
__global__ __launch_bounds__(256) void prep(
        const float* __restrict__ nf, const float* __restrict__ W1,
        const float* __restrict__ W2, int* __restrict__ cursor,
        unsigned short* __restrict__ catHi, unsigned short* __restrict__ catLo,
        unsigned short* __restrict__ W1tHi, unsigned short* __restrict__ W1tLo,
        unsigned short* __restrict__ W2tHi, unsigned short* __restrict__ W2tLo,
        int n) {
    int flat = blockIdx.x * 256 + threadIdx.x;
    if (flat < n) cursor[flat] = 0;
    if (flat < 512 * 256) {                    // W1t idx = nn*512 + k
        int nn = flat >> 9, k = flat & 511;
        unsigned short hi, lo;
        split2(W1[(size_t)k * 256 + nn], hi, lo);
        W1tHi[flat] = hi; W1tLo[flat] = lo;
    } else if (flat < 512 * 256 + 256 * 256) { // W2t idx2 = nn*256 + k
        int idx2 = flat - 512 * 256;
        int nn = idx2 >> 8, k = idx2 & 255;
        unsigned short hi, lo;
        split2(W2[(size_t)k * 256 + nn], hi, lo);
        W2tHi[idx2] = hi; W2tLo[idx2] = lo;
    }
    int wid  = threadIdx.x >> 6;
    int lane = threadIdx.x & 63;
    int row  = blockIdx.x * 4 + wid;
    if (row < n) {
        float4 v = ((const float4*)nf)[(size_t)row * 64 + lane];
        ushort4 hi, lo;
        split2(v.x, hi.x, lo.x); split2(v.y, hi.y, lo.y);
        split2(v.z, hi.z, lo.z); split2(v.w, hi.w, lo.w);
        size_t base = (size_t)row * 512 + lane * 4;
        *(ushort4*)&catHi[base] = hi;
        *(ushort4*)&catLo[base] = lo;
    }
}

// ---------------------------------------------------------------------------
__global__ void scatter_edges(const int* __restrict__ esrc, const int* __restrict__ edst,
                              int* __restrict__ cursor, int* __restrict__ bucket, int E) {
    int e = blockIdx.x * 256 + threadIdx.x;
    if (e >= E) return;
    int d = edst[e];
    int s = esrc[e];
    int r = atomicAdd(&cursor[d], 1);
    if (r < MAXDEG) bucket[d * MAXDEG + r] = s;
}

// ---------------------------------------------------------------------------
// pooled[i] = deg_i*nf[i] (fp32) - sum_{src} bf16(nf[src]); gathers 512B bf16
// rows from catHi cols [0,256); writes hi/lo into cat cols [256,512).
__global__ __launch_bounds__(256) void agg_kernel(
        const float* __restrict__ nf, const int* __restrict__ cursor,
        const int* __restrict__ bucket, unsigned short* __restrict__ catHi,
        unsigned short* __restrict__ catLo, int n) {
    int wid  = threadIdx.x >> 6;
    int lane = threadIdx.x & 63;
    int node = blockIdx.x * 4 + wid;
    if (node >= n) return;
    int deg  = cursor[node];
    int degc = deg < MAXDEG ? deg : MAXDEG;
    const int* bk = bucket + (size_t)node * MAXDEG;
    float4 acc = make_float4(0.f, 0.f, 0.f, 0.f);
    int e = 0;
    for (; e + 4 <= degc; e += 4) {
        int s0 = bk[e], s1 = bk[e+1], s2 = bk[e+2], s3 = bk[e+3];
        uint2 v0 = *(const uint2*)&catHi[(size_t)s0 * 512 + lane * 4];
        uint2 v1 = *(const uint2*)&catHi[(size_t)s1 * 512 + lane * 4];
        uint2 v2 = *(const uint2*)&catHi[(size_t)s2 * 512 + lane * 4];
        uint2 v3 = *(const uint2*)&catHi[(size_t)s3 * 512 + lane * 4];
        acc.x += (u2f_lo(v0.x) + u2f_lo(v1.x)) + (u2f_lo(v2.x) + u2f_lo(v3.x));
        acc.y += (u2f_hi(v0.x) + u2f_hi(v1.x)) + (u2f_hi(v2.x) + u2f_hi(v3.x));
        acc.z += (u2f_lo(v0.y) + u2f_lo(v1.y)) + (u2f_lo(v2.y) + u2f_lo(v3.y));
        acc.w += (u2f_hi(v0.y) + u2f_hi(v1.y)) + (u2f_hi(v2.y) + u2f_hi(v3.y));
    }
    for (; e < degc; ++e) {
        int s = bk[e];
        uint2 v = *(const uint2*)&catHi[(size_t)s * 512 + lane * 4];
        acc.x += u2f_lo(v.x); acc.y += u2f_hi(v.x);
        acc.z += u2f_lo(v.y); acc.w += u2f_hi(v.y);
    }
    float4 self = ((const float4*)nf)[(size_t)node * 64 + lane];
    float fd = (float)deg;
    float4 outv;
    outv.x = fd * self.x - acc.x;
    outv.y = fd * self.y - acc.y;
    outv.z = fd * self.z - acc.z;
    outv.w = fd * self.w - acc.w;
    ushort4 hi, lo;
    split2(outv.x, hi.x, lo.x); split2(outv.y, hi.y, lo.y);
    split2(outv.z, hi.z, lo.z); split2(outv.w, hi.w, lo.w);
    size_t base = (size_t)node * 512 + 256 + lane * 4;
    *(ushort4*)&catHi[base] = hi;
    *(ushort4*)&catLo[base] = lo;
}

// ---------------------------------------------------------------------------
// Fused split-bf16 MFMA GEMM: out = tanh((cat@W1+b1)@W2 + b2).
// Block: 256 thr / 4 waves, M-tile 64, N=256 (wave w owns n-cols [64w,64w+64)).
// All A/B fragments load straight from global (L2-resident; b128 per lane, 64B
// segments fully consumed). h handed stage1->stage2 through 80KB LDS in the
// stride-40 chunked layout (throughput-floor-clean). No K-loop barriers.
// 3-term split product: Ahi*Bhi + Ahi*Blo + Alo*Bhi.
#define LDSTH 40
__global__ __launch_bounds__(256, 2) void gemm12(
        const unsigned short* __restrict__ Ahi, const unsigned short* __restrict__ Alo,
        const unsigned short* __restrict__ W1h, const unsigned short* __restrict__ W1l,
        const unsigned short* __restrict__ W2h, const unsigned short* __restrict__ W2l,
        const float* __restrict__ b1, const float* __restrict__ b2,
        float* __restrict__ out, int M) {
    __shared__ unsigned short hbuf[2][8][64 * LDSTH];  // 81920 B = 2 blocks/CU

    int tid = threadIdx.x, lane = tid & 63, wid = tid >> 6;
    int m0 = blockIdx.x * 64;
    int wn = wid * 64;
    int fm = lane & 15;
    int q  = lane >> 4;
    int fk = q * 8;

    // ---- stage 1: h[64][256] = cat[64][512] @ W1t + b1 ----
    size_t arow[4], brow[4];
#pragma unroll
    for (int i = 0; i < 4; ++i) {
        int r = m0 + i * 16 + fm; if (r >= M) r = M - 1;   // clamp; junk rows unused
        arow[i] = (size_t)r * 512 + fk;
    }
#pragma unroll
    for (int j = 0; j < 4; ++j) brow[j] = (size_t)(wn + j * 16 + fm) * 512 + fk;

    f32x4 acc[4][4] = {};
#pragma unroll 2
    for (int kb = 0; kb < 512; kb += 32) {
        bf16x8 ah[4], al[4], bh[4], bl[4];
#pragma unroll
        for (int i = 0; i < 4; ++i) {
            ah[i] = *(const bf16x8*)&Ahi[arow[i] + kb];
            al[i] = *(const bf16x8*)&Alo[arow[i] + kb];
        }
#pragma unroll
        for (int j = 0; j < 4; ++j) {
            bh[j] = *(const bf16x8*)&W1h[brow[j] + kb];
            bl[j] = *(const bf16x8*)&W1l[brow[j] + kb];
        }
#pragma unroll
        for (int i = 0; i < 4; ++i)
#pragma unroll
            for (int j = 0; j < 4; ++j) {
                acc[i][j] = __builtin_amdgcn_mfma_f32_16x16x32_bf16(ah[i], bh[j], acc[i][j], 0, 0, 0);
                acc[i][j] = __builtin_amdgcn_mfma_f32_16x16x32_bf16(ah[i], bl[j], acc[i][j], 0, 0, 0);
                acc[i][j] = __builtin_amdgcn_mfma_f32_16x16x32_bf16(al[i], bh[j], acc[i][j], 0, 0, 0);
            }
    }

    // epilogue 1: split h into hbuf (chunked [k/32][row][k%32], stride 40)
#pragma unroll
    for (int j = 0; j < 4; ++j) {
        int ncol = wn + j * 16 + fm;          // stage-2 k index
        float bv = b1[ncol];
        int chunk = ncol >> 5, cc = ncol & 31;
#pragma unroll
        for (int i = 0; i < 4; ++i) {
#pragma unroll
            for (int r = 0; r < 4; ++r) {
                int row = i * 16 + q * 4 + r;
                float v = acc[i][j][r] + bv;
                unsigned short hi, lo;
                split2(v, hi, lo);
                hbuf[0][chunk][row * LDSTH + cc] = hi;
                hbuf[1][chunk][row * LDSTH + cc] = lo;
            }
        }
    }
    __syncthreads();

    // ---- stage 2: out[64][256] = tanh(h @ W2t + b2) ----
    size_t brow2[4];
#pragma unroll
    for (int j = 0; j < 4; ++j) brow2[j] = (size_t)(wn + j * 16 + fm) * 256 + fk;

    f32x4 acc2[4][4] = {};
#pragma unroll 2
    for (int kb = 0; kb < 256; kb += 32) {
        int chunk = kb >> 5;
        bf16x8 ah[4], al[4], bh[4], bl[4];
#pragma unroll
        for (int i = 0; i < 4; ++i) {
            ah[i] = *(const bf16x8*)&hbuf[0][chunk][(i * 16 + fm) * LDSTH + fk];
            al[i] = *(const bf16x8*)&hbuf[1][chunk][(i * 16 + fm) * LDSTH + fk];
        }
#pragma unroll
        for (int j = 0; j < 4; ++j) {
            bh[j] = *(const bf16x8*)&W2h[brow2[j] + kb];
            bl[j] = *(const bf16x8*)&W2l[brow2[j] + kb];
        }
#pragma unroll
        for (int i = 0; i < 4; ++i)
#pragma unroll
            for (int j = 0; j < 4; ++j) {
                acc2[i][j] = __builtin_amdgcn_mfma_f32_16x16x32_bf16(ah[i], bh[j], acc2[i][j], 0, 0, 0);
                acc2[i][j] = __builtin_amdgcn_mfma_f32_16x16x32_bf16(ah[i], bl[j], acc2[i][j], 0, 0, 0);
                acc2[i][j] = __builtin_amdgcn_mfma_f32_16x16x32_bf16(al[i], bh[j], acc2[i][j], 0, 0, 0);
            }
    }

    // epilogue 2
#pragma unroll
    for (int j = 0; j < 4; ++j) {
        int ncol = wn + j * 16 + fm;
        float bv = b2[ncol];
#pragma unroll
        for (int i = 0; i < 4; ++i) {
#pragma unroll
            for (int r = 0; r < 4; ++r) {
                int row = m0 + i * 16 + q * 4 + r;
                if (row < M) out[(size_t)row * 256 + ncol] = tanhf(acc2[i][j][r] + bv);
            }
        }
    }
}

// ---------------------------------------------------------------------------
extern "C" void kernel_launch(void* const* d_in, const int* in_sizes, int n_in,
                              void* d_out, int out_size, void* d_ws, size_t ws_size,
                              hipStream_t stream) {
    const float* nf  = (const float*)d_in[0];   // [N, 256] fp32
    const float* W1  = (const float*)d_in[1];   // [512, 256]
    const float* b1  = (const float*)d_in[2];   // [256]
    const float* W2  = (const float*)d_in[3];   // [256, 256]
    const float* b2  = (const float*)d_in[4];   // [256]
    const int* esrc  = (const int*)d_in[5];     // [E]
    const int* edst  = (const int*)d_in[6];     // [E]
    float* out = (float*)d_out;                 // [N, 256] fp32

    int N = in_sizes[0] / H2;
    int E = in_sizes[5];

    char* ws = (char*)d_ws;
    size_t off = 0;
    auto take = [&](size_t bytes) { size_t o = off; off += (bytes + 255) / 256 * 256; return o; };
    int*            cursor = (int*)(ws + take((size_t)N * 4));
    int*            bucket = (int*)(ws + take((size_t)N * MAXDEG * 4));
    unsigned short* catHi  = (unsigned short*)(ws + take((size_t)N * 512 * 2));
    unsigned short* catLo  = (unsigned short*)(ws + take((size_t)N * 512 * 2));
    unsigned short* W1tHi  = (unsigned short*)(ws + take(512 * 256 * 2));
    unsigned short* W1tLo  = (unsigned short*)(ws + take(512 * 256 * 2));
    unsigned short* W2tHi  = (unsigned short*)(ws + take(256 * 256 * 2));
    unsigned short* W2tLo  = (unsigned short*)(ws + take(256 * 256 * 2));

    prep<<<(N + 3) / 4, 256, 0, stream>>>(nf, W1, W2, cursor, catHi, catLo,
                                          W1tHi, W1tLo, W2tHi, W2tLo, N);
    scatter_edges<<<(E + 255) / 256, 256, 0, stream>>>(esrc, edst, cursor, bucket, E);
    agg_kernel<<<(N + 3) / 4, 256, 0, stream>>>(nf, cursor, bucket, catHi, catLo, N);
    gemm12<<<(N + 63) / 64, 256, 0, stream>>>(catHi, catLo, W1tHi, W1tLo,
                                              W2tHi, W2tLo, b1, b2, out, N);
}